// Round 6
// baseline (963.116 us; speedup 1.0000x reference)
//
#include <hip/hip_runtime.h>
#include <cstdint>
#include <cstddef>

typedef __bf16 bf16;
typedef __bf16 bf16x8 __attribute__((ext_vector_type(8)));
typedef float f32x4 __attribute__((ext_vector_type(4)));

#define GLD_LDS16(gp, lp)                                                              \
  __builtin_amdgcn_global_load_lds((const __attribute__((address_space(1))) void*)(gp), \
                                   (__attribute__((address_space(3))) void*)(lp), 16, 0, 0)

namespace {
constexpr int kN  = 16384;
constexpr int kF  = 39;
constexpr int kV  = 100000;
constexpr int kE  = 16;
constexpr int kD  = 624;
constexpr int kDP = 640;   // D padded to multiple of 128
constexpr int kL  = 5;
}

// ---------------------------------------------------------------------------
// Weight convert: f32 W[l][k][j] -> bf16 Wt[j][k], zero-padded to 640x640.
// 20 matrices laid out [type*5 + layer][640][640].
// ---------------------------------------------------------------------------
__global__ void wconv_kernel(const float* __restrict__ Wq, const float* __restrict__ Wk,
                             const float* __restrict__ Wv, const float* __restrict__ Wo,
                             bf16* __restrict__ wt) {
  const int mi  = blockIdx.y;         // 0..19
  const int typ = mi / 5, lay = mi % 5;
  const float* W = (typ == 0 ? Wq : typ == 1 ? Wk : typ == 2 ? Wv : Wo) + (size_t)lay * kD * kD;
  bf16* dst = wt + (size_t)mi * kDP * kDP;
  const int bj = blockIdx.x % 20;     // j tile
  const int bk = blockIdx.x / 20;     // k tile
  __shared__ float tl[32][33];
  const int tx = threadIdx.x & 31, ty = threadIdx.x >> 5;
#pragma unroll
  for (int i = 0; i < 4; ++i) {
    const int k = bk * 32 + ty + i * 8;
    const int j = bj * 32 + tx;
    tl[ty + i * 8][tx] = (k < kD && j < kD) ? W[k * kD + j] : 0.f;
  }
  __syncthreads();
#pragma unroll
  for (int i = 0; i < 4; ++i) {
    const int j = bj * 32 + ty + i * 8;
    const int k = bk * 32 + tx;
    dst[j * kDP + k] = (bf16)tl[tx][ty + i * 8];
  }
}

// ---------------------------------------------------------------------------
// Embedding gather + per-(n,e) normalization over F; produces
//   f1[n][40], f2[n][16] (f32, exact) and x (bf16, [n][640], cols 624..639 = 0)
// One wave per sample, 4 waves per block.
// ---------------------------------------------------------------------------
__global__ void embed_kernel(const int* __restrict__ Xi, const float* __restrict__ Xv,
                             const float* __restrict__ emb1, const float* __restrict__ emb2,
                             bf16* __restrict__ xb, float* __restrict__ f1, float* __restrict__ f2) {
  const int wid = threadIdx.x >> 6, lane = threadIdx.x & 63;
  const int n = blockIdx.x * 4 + wid;
  __shared__ float xv_s[4][kF][kE];
  __shared__ float inv_s[4][kE];
  const int g = lane >> 4, e = lane & 15;
#pragma unroll
  for (int fb = 0; fb < 10; ++fb) {
    const int f = fb * 4 + g;
    if (f < kF) {
      const int idx   = Xi[n * kF + f];
      const float sc  = Xv[n * kF + f];
      const float v   = emb2[(f * kV + idx) * kE + e] * sc;   // coalesced 64B per 16-lane group
      xv_s[wid][f][e] = v;
      if (e == 0) f1[n * 40 + f] = emb1[f * kV + idx] * sc;
    }
  }
  __syncthreads();
  if (lane < kE) {
    float s = 0.f, s2 = 0.f;
    for (int f = 0; f < kF; ++f) { const float v = xv_s[wid][f][lane]; s += v; s2 += v * v; }
    const float nrm = fmaxf(sqrtf(s2), 1e-12f);
    const float inv = 1.f / nrm;
    inv_s[wid][lane] = inv;
    const float s1 = s * inv;
    f2[n * kE + lane] = 0.5f * (s1 * s1 - s2 * inv * inv);
  }
  __syncthreads();
  const float inv = inv_s[wid][e];
#pragma unroll
  for (int fb = 0; fb < 10; ++fb) {
    const int f = fb * 4 + g;
    if (f < kF) xb[(size_t)n * kDP + f * kE + e] = (bf16)(xv_s[wid][f][e] * inv);
  }
  if (lane < 16) xb[(size_t)n * kDP + kD + lane] = (bf16)0.f;  // zero the K-pad
}

// ---------------------------------------------------------------------------
// bf16 MFMA GEMM: D[16384][640] = A[16384][640] @ Bt^T  (Bt stored [j][k])
// 128x128 tile, BK=32, 4 waves (2x2 of 64x64), global_load_lds staging,
// XOR slot-swizzle (inverse-swizzled global source, swizzled ds_read).
// MODE 0: D = A@B + bias.  MODE 1: D = (A@B + bias) * scores[row][col/16].
// ---------------------------------------------------------------------------
template <int MODE>
__global__ __launch_bounds__(256) void gemm_kernel(const bf16* __restrict__ A,
                                                   const bf16* __restrict__ Bt,
                                                   const float* __restrict__ bias,
                                                   const float* __restrict__ scr,
                                                   bf16* __restrict__ Dst) {
  __shared__ bf16 As[128 * 32];
  __shared__ bf16 Bs[128 * 32];
  const int lane = threadIdx.x & 63;
  const int wid  = threadIdx.x >> 6;
  const int wm = wid >> 1, wn = wid & 1;
  const int row0 = blockIdx.x * 128;
  const int col0 = blockIdx.y * 128;

  f32x4 acc[4][4] = {};

  // staging geometry: each wave fills 2 chunks of 16 rows x 32 k (1KB each).
  // LDS dest is linear (wave base + lane*16 implicit); the 16B slot within each
  // 64B row is fetched pre-swizzled so that swizzled reads are conflict-free.
  const int lr  = lane >> 2;                    // row within chunk
  const int sl  = lane & 3;                     // physical 16B slot
  const int lsl = sl ^ ((lr >> 1) & 3);         // logical slot to fetch
  const size_t aoff0 = (size_t)(row0 + wid * 32 +      lr) * kDP + lsl * 8;
  const size_t aoff1 = (size_t)(row0 + wid * 32 + 16 + lr) * kDP + lsl * 8;
  const size_t boff0 = (size_t)(col0 + wid * 32 +      lr) * kDP + lsl * 8;
  const size_t boff1 = (size_t)(col0 + wid * 32 + 16 + lr) * kDP + lsl * 8;
  bf16* asd0 = As + wid * 1024;
  bf16* asd1 = As + wid * 1024 + 512;
  bf16* bsd0 = Bs + wid * 1024;
  bf16* bsd1 = Bs + wid * 1024 + 512;

  const int rsel = lane & 15;
  const int roff = ((lane >> 4) ^ ((rsel >> 1) & 3)) * 8;   // swizzled read slot

  for (int kt = 0; kt < kDP / 32; ++kt) {
    const int k0 = kt * 32;
    GLD_LDS16(A  + aoff0 + k0, asd0);
    GLD_LDS16(A  + aoff1 + k0, asd1);
    GLD_LDS16(Bt + boff0 + k0, bsd0);
    GLD_LDS16(Bt + boff1 + k0, bsd1);
    __syncthreads();
    bf16x8 av[4], bvv[4];
#pragma unroll
    for (int m = 0; m < 4; ++m)
      av[m] = *(const bf16x8*)(As + (wm * 64 + m * 16 + rsel) * 32 + roff);
#pragma unroll
    for (int nn = 0; nn < 4; ++nn)
      bvv[nn] = *(const bf16x8*)(Bs + (wn * 64 + nn * 16 + rsel) * 32 + roff);
#pragma unroll
    for (int m = 0; m < 4; ++m)
#pragma unroll
      for (int nn = 0; nn < 4; ++nn)
        acc[m][nn] = __builtin_amdgcn_mfma_f32_16x16x32_bf16(av[m], bvv[nn], acc[m][nn], 0, 0, 0);
    __syncthreads();
  }

  const int crow = (lane >> 4) * 4;
  const int ccol = lane & 15;
#pragma unroll
  for (int m = 0; m < 4; ++m) {
#pragma unroll
    for (int nn = 0; nn < 4; ++nn) {
      const int gcol = col0 + wn * 64 + nn * 16 + ccol;
      const float bb = (gcol < kD) ? bias[gcol] : 0.f;
#pragma unroll
      for (int r = 0; r < 4; ++r) {
        const int grow = row0 + wm * 64 + m * 16 + crow + r;
        float v = acc[m][nn][r] + bb;
        if (MODE == 1) v *= (gcol < kD) ? scr[grow * 40 + (gcol >> 4)] : 0.f;
        Dst[(size_t)grow * kDP + gcol] = (bf16)v;
      }
    }
  }
}

// scores[n][h] = 0.25 * sum_{i<16} q[n][h*16+i] * k[n][h*16+i]
__global__ void scores_kernel(const bf16* __restrict__ q, const bf16* __restrict__ k,
                              float* __restrict__ s) {
  const int t = blockIdx.x * 256 + threadIdx.x;   // exact: N*F = 2496*256
  const int n = t / kF;
  const int h = t - n * kF;
  const bf16x8* qp = (const bf16x8*)(q + (size_t)n * kDP + h * 16);
  const bf16x8* kp = (const bf16x8*)(k + (size_t)n * kDP + h * 16);
  const bf16x8 q0 = qp[0], q1 = qp[1];
  const bf16x8 k0 = kp[0], k1 = kp[1];
  float acc = 0.f;
#pragma unroll
  for (int i = 0; i < 8; ++i) acc += (float)q0[i] * (float)k0[i] + (float)q1[i] * (float)k1[i];
  s[n * 40 + h] = acc * 0.25f;
}

// ---------------------------------------------------------------------------
// Head: h1=f1@m1_w, h2=f2@m2_w, h3=out@m3_w, 12x12 FFW + relu, 12x2 final.
// One wave per sample.
// ---------------------------------------------------------------------------
__global__ void head_kernel(const bf16* __restrict__ outb, const float* __restrict__ f1,
                            const float* __restrict__ f2,
                            const float* __restrict__ m1w, const float* __restrict__ m1b,
                            const float* __restrict__ m2w, const float* __restrict__ m2b,
                            const float* __restrict__ m3w, const float* __restrict__ m3b,
                            const float* __restrict__ fww, const float* __restrict__ fwb,
                            const float* __restrict__ fdw, const float* __restrict__ fdb,
                            float* __restrict__ out) {
  const int wid = threadIdx.x >> 6, lane = threadIdx.x & 63;
  const int n = blockIdx.x * 4 + wid;
  float acc[12];
#pragma unroll
  for (int i = 0; i < 12; ++i) acc[i] = 0.f;
  for (int d = lane; d < kD; d += 64) {
    const float v = (float)outb[(size_t)n * kDP + d];
#pragma unroll
    for (int c = 0; c < 4; ++c) acc[8 + c] += v * m3w[d * 4 + c];
  }
  if (lane < kF) {
    const float v = f1[n * 40 + lane];
#pragma unroll
    for (int c = 0; c < 4; ++c) acc[c] += v * m1w[lane * 4 + c];
  }
  if (lane < kE) {
    const float v = f2[n * kE + lane];
#pragma unroll
    for (int c = 0; c < 4; ++c) acc[4 + c] += v * m2w[lane * 4 + c];
  }
#pragma unroll
  for (int off = 32; off > 0; off >>= 1) {
#pragma unroll
    for (int i = 0; i < 12; ++i) acc[i] += __shfl_down(acc[i], off);
  }
  if (lane == 0) {
    float in[12];
#pragma unroll
    for (int c = 0; c < 4; ++c) {
      in[c]     = acc[c]     + m1b[c];
      in[4 + c] = acc[4 + c] + m2b[c];
      in[8 + c] = acc[8 + c] + m3b[c];
    }
    float o0 = fdb[0], o1 = fdb[1];
#pragma unroll
    for (int j = 0; j < 12; ++j) {
      float h = fwb[j];
#pragma unroll
      for (int i = 0; i < 12; ++i) h += in[i] * fww[i * 12 + j];
      h = fmaxf(h, 0.f);
      o0 += h * fdw[j * 2 + 0];
      o1 += h * fdw[j * 2 + 1];
    }
    out[n * 2 + 0] = o0;
    out[n * 2 + 1] = o1;
  }
}

// ---------------------------------------------------------------------------
extern "C" void kernel_launch(void* const* d_in, const int* in_sizes, int n_in,
                              void* d_out, int out_size, void* d_ws, size_t ws_size,
                              hipStream_t stream) {
  (void)in_sizes; (void)n_in; (void)out_size; (void)ws_size;
  const int*   Xi   = (const int*)d_in[0];
  const float* Xv   = (const float*)d_in[1];
  const float* emb1 = (const float*)d_in[2];
  const float* emb2 = (const float*)d_in[3];
  const float* Wq   = (const float*)d_in[4];
  const float* bq   = (const float*)d_in[5];
  const float* Wk   = (const float*)d_in[6];
  const float* bk   = (const float*)d_in[7];
  const float* Wv   = (const float*)d_in[8];
  const float* bv   = (const float*)d_in[9];
  const float* Wo   = (const float*)d_in[10];
  const float* bo   = (const float*)d_in[11];
  const float* m1w  = (const float*)d_in[12];
  const float* m1b  = (const float*)d_in[13];
  const float* m2w  = (const float*)d_in[14];
  const float* m2b  = (const float*)d_in[15];
  const float* m3w  = (const float*)d_in[16];
  const float* m3b  = (const float*)d_in[17];
  const float* fww  = (const float*)d_in[18];
  const float* fwb  = (const float*)d_in[19];
  const float* fdw  = (const float*)d_in[20];
  const float* fdb  = (const float*)d_in[21];

  char* p = (char*)d_ws;
  auto carve = [&](size_t bytes) { char* r = p; p += (bytes + 255) & ~(size_t)255; return r; };
  bf16*  wt   = (bf16*)carve((size_t)20 * kDP * kDP * sizeof(bf16));
  bf16*  xb   = (bf16*)carve((size_t)kN * kDP * sizeof(bf16));
  bf16*  outb = (bf16*)carve((size_t)kN * kDP * sizeof(bf16));
  bf16*  qb   = (bf16*)carve((size_t)kN * kDP * sizeof(bf16));   // reused as att
  bf16*  kbuf = (bf16*)carve((size_t)kN * kDP * sizeof(bf16));
  float* scr  = (float*)carve((size_t)kN * 40 * sizeof(float));
  float* f1b  = (float*)carve((size_t)kN * 40 * sizeof(float));
  float* f2b  = (float*)carve((size_t)kN * kE * sizeof(float));

  wconv_kernel<<<dim3(400, 20), 256, 0, stream>>>(Wq, Wk, Wv, Wo, wt);
  embed_kernel<<<kN / 4, 256, 0, stream>>>(Xi, Xv, emb1, emb2, xb, f1b, f2b);

  const dim3 ggrid(kN / 128, kDP / 128);
  const size_t wsz = (size_t)kDP * kDP;
  for (int l = 0; l < kL; ++l) {
    gemm_kernel<0><<<ggrid, 256, 0, stream>>>(xb, wt + (size_t)(0 * 5 + l) * wsz, bq + l * kD, nullptr, qb);
    gemm_kernel<0><<<ggrid, 256, 0, stream>>>(xb, wt + (size_t)(1 * 5 + l) * wsz, bk + l * kD, nullptr, kbuf);
    scores_kernel<<<kN * kF / 256, 256, 0, stream>>>(qb, kbuf, scr);
    gemm_kernel<1><<<ggrid, 256, 0, stream>>>(l == 0 ? xb : outb, wt + (size_t)(2 * 5 + l) * wsz,
                                              bv + l * kD, scr, qb);
    gemm_kernel<0><<<ggrid, 256, 0, stream>>>(qb, wt + (size_t)(3 * 5 + l) * wsz, bo + l * kD, nullptr, outb);
  }
  head_kernel<<<kN / 4, 256, 0, stream>>>(outb, f1b, f2b, m1w, m1b, m2w, m2b, m3w, m3b,
                                          fww, fwb, fdw, fdb, (float*)d_out);
}